// Round 2
// baseline (710.905 us; speedup 1.0000x reference)
//
#include <hip/hip_runtime.h>

// VQ-VAE codebook quantization.
// x: (4096, 1024) f32; codebook: (128, 256, 8) f32.
// out = [cw_embed (4096*1024 f32) | one_hot (4096*128*256 f32)].
//
// Write-bound: one_hot is 536.9 MB -> floor ~91 us at 6.3 TB/s.
// Distances computed in FP64 so the argmin is the TRUE argmin: fp32
// formulations flip near-ties (~5e-6 noise vs O(1) gaps; a few flips per
// 524288 argmins) vs the numpy reference — that was R1's failure mode.
// Block = (one c) x (1024 b). Codebook slice staged in LDS (f32 + f64 + c2).

constexpr int B_    = 4096;
constexpr int C_    = 128;
constexpr int K_    = 256;
constexpr int D_    = 8;
constexpr int TPB   = 256;   // threads per block
constexpr int BPT   = 4;     // b's per thread (fp64 x-frags: 64 VGPRs)
constexpr int BTILE = TPB * BPT; // 1024 b per block

__global__ __launch_bounds__(TPB, 2) void vq_kernel(
    const float* __restrict__ x,
    const float* __restrict__ cb,
    float* __restrict__ out_embed,
    float* __restrict__ out_onehot)
{
    __shared__ float  s_cbf[K_ * D_];  //  8 KB: f32 slice (for embed gather)
    __shared__ double s_cbd[K_ * D_];  // 16 KB: f64 slice (for distances)
    __shared__ double s_c2d[K_];       //  2 KB: ||c_k||^2 in f64

    const int c     = blockIdx.x;    // 0..127
    const int btile = blockIdx.y;    // 0..3
    const int tid   = threadIdx.x;

    // ---- stage codebook slice (2048 floats = 512 float4), f32 + f64 ----
    {
        const float4* gcb = (const float4*)(cb + (size_t)c * (K_ * D_));
        const float4 v0 = gcb[tid];
        const float4 v1 = gcb[tid + TPB];
        ((float4*)s_cbf)[tid]       = v0;
        ((float4*)s_cbf)[tid + TPB] = v1;
        const int i0 = tid * 4, i1 = (tid + TPB) * 4;
        s_cbd[i0 + 0] = (double)v0.x;
        s_cbd[i0 + 1] = (double)v0.y;
        s_cbd[i0 + 2] = (double)v0.z;
        s_cbd[i0 + 3] = (double)v0.w;
        s_cbd[i1 + 0] = (double)v1.x;
        s_cbd[i1 + 1] = (double)v1.y;
        s_cbd[i1 + 2] = (double)v1.z;
        s_cbd[i1 + 3] = (double)v1.w;
    }
    __syncthreads();

    // ---- c2[k] = sum_d cb[c,k,d]^2 in f64 (one k per thread) ----
    {
        const double* v = s_cbd + tid * D_;
        double s = 0.0;
        #pragma unroll
        for (int d = 0; d < D_; ++d) s = fma(v[d], v[d], s);
        s_c2d[tid] = s;
    }
    __syncthreads();

    // ---- load x fragments: 4 b's, 8 floats each -> f64 registers ----
    double xd[BPT][D_];
    #pragma unroll
    for (int j = 0; j < BPT; ++j) {
        const int b = btile * BTILE + j * TPB + tid;
        const float4* xp = (const float4*)(x + (size_t)b * (C_ * D_) + c * D_);
        const float4 a = xp[0];
        const float4 h = xp[1];
        xd[j][0] = (double)a.x; xd[j][1] = (double)a.y;
        xd[j][2] = (double)a.z; xd[j][3] = (double)a.w;
        xd[j][4] = (double)h.x; xd[j][5] = (double)h.y;
        xd[j][6] = (double)h.z; xd[j][7] = (double)h.w;
    }

    double best[BPT];
    int    bidx[BPT];
    #pragma unroll
    for (int j = 0; j < BPT; ++j) { best[j] = 1.0e300; bidx[j] = 0; }

    // ---- argmin over K codes; score = c2[k] - 2*dot (x2 is k-constant).
    // All f64: true argmin, immune to fp32 rounding-order tie flips.
    // Strict < keeps the FIRST minimal index (numpy argmin semantics).
    for (int k = 0; k < K_; ++k) {
        double cd[D_];
        #pragma unroll
        for (int d = 0; d < D_; ++d) cd[d] = s_cbd[k * D_ + d];
        const double c2k = s_c2d[k];
        #pragma unroll
        for (int j = 0; j < BPT; ++j) {
            double dot = xd[j][0] * cd[0];
            #pragma unroll
            for (int d = 1; d < D_; ++d) dot = fma(xd[j][d], cd[d], dot);
            const double score = fma(-2.0, dot, c2k);
            if (score < best[j]) { best[j] = score; bidx[j] = k; }
        }
    }

    // ---- epilogue: embed gather + one-hot rows ----
    const float4* scbf4 = (const float4*)s_cbf;
    #pragma unroll
    for (int j = 0; j < BPT; ++j) {
        const int    b    = btile * BTILE + j * TPB + tid;
        const size_t pair = (size_t)b * C_ + c;
        const int    kmin = bidx[j];

        // cw_embed[b, c*8 .. c*8+8] = codebook[c, kmin, :]
        float4* dst = (float4*)(out_embed + pair * D_);
        dst[0] = scbf4[kmin * 2];
        dst[1] = scbf4[kmin * 2 + 1];

        // one_hot[b, c, :] : 64 float4 stores, branchless select
        float4* oh = (float4*)(out_onehot + pair * K_);
        const int ch = kmin >> 2;
        const int r  = kmin & 3;
        float4 one4;
        one4.x = (r == 0) ? 1.f : 0.f;
        one4.y = (r == 1) ? 1.f : 0.f;
        one4.z = (r == 2) ? 1.f : 0.f;
        one4.w = (r == 3) ? 1.f : 0.f;
        const float4 zero4 = make_float4(0.f, 0.f, 0.f, 0.f);
        #pragma unroll 8
        for (int t = 0; t < K_ / 4; ++t) {
            oh[t] = (t == ch) ? one4 : zero4;
        }
    }
}

extern "C" void kernel_launch(void* const* d_in, const int* in_sizes, int n_in,
                              void* d_out, int out_size, void* d_ws, size_t ws_size,
                              hipStream_t stream) {
    const float* x  = (const float*)d_in[0];
    const float* cb = (const float*)d_in[1];
    float* out        = (float*)d_out;
    float* out_embed  = out;                              // 4096*1024
    float* out_onehot = out + (size_t)B_ * C_ * D_;       // 4096*128*256

    dim3 grid(C_, B_ / BTILE);  // (128, 4) = 512 blocks
    vq_kernel<<<grid, TPB, 0, stream>>>(x, cb, out_embed, out_onehot);
}

// Round 3
// 617.811 us; speedup vs baseline: 1.1507x; 1.1507x over previous
//
#include <hip/hip_runtime.h>

// VQ-VAE codebook quantization — two-kernel split.
// x: (4096, 1024) f32; codebook: (128, 256, 8) f32.
// out = [cw_embed (4096*1024 f32) | one_hot (4096*128*256 f32)].
//
// R2 post-mortem: single kernel hit 711 us because every one-hot/embed/x
// access scattered 64 lanes across 64 distinct pages (128KB lane stride) —
// transaction/TLB-bound, not BW-bound. Fix: K1 computes argmin (fp64, exact
// match with numpy ref — R2 absmax was 0.0) and writes only a 2MB idx array;
// K2 streams the 554MB of outputs with one fully-coalesced 1KB row per
// wave-store instruction.

constexpr int B_    = 4096;
constexpr int C_    = 128;
constexpr int K_    = 256;
constexpr int D_    = 8;
constexpr int TPB   = 256;
constexpr int BPT   = 4;          // b's per thread in K1
constexpr int BTILE = TPB * BPT;  // 1024 b per K1 block

// ---------------- K1: fp64 argmin -> idx[b*128 + c] ----------------
__global__ __launch_bounds__(TPB, 2) void vq_argmin(
    const float* __restrict__ x,
    const float* __restrict__ cb,
    int* __restrict__ idx_out)
{
    __shared__ double s_cbd[K_ * D_];  // 16 KB fp64 codebook slice
    __shared__ double s_c2d[K_];       //  2 KB ||c_k||^2

    const int c     = blockIdx.x;  // 0..127
    const int btile = blockIdx.y;  // 0..3
    const int tid   = threadIdx.x;

    // stage codebook slice (2048 floats) as fp64
    {
        const float4* gcb = (const float4*)(cb + (size_t)c * (K_ * D_));
        const float4 v0 = gcb[tid];
        const float4 v1 = gcb[tid + TPB];
        const int i0 = tid * 4, i1 = (tid + TPB) * 4;
        s_cbd[i0 + 0] = (double)v0.x; s_cbd[i0 + 1] = (double)v0.y;
        s_cbd[i0 + 2] = (double)v0.z; s_cbd[i0 + 3] = (double)v0.w;
        s_cbd[i1 + 0] = (double)v1.x; s_cbd[i1 + 1] = (double)v1.y;
        s_cbd[i1 + 2] = (double)v1.z; s_cbd[i1 + 3] = (double)v1.w;
    }
    __syncthreads();

    {
        const double* v = s_cbd + tid * D_;
        double s = 0.0;
        #pragma unroll
        for (int d = 0; d < D_; ++d) s = fma(v[d], v[d], s);
        s_c2d[tid] = s;
    }
    __syncthreads();

    // x fragments: 4 b's, 8 floats each -> fp64 regs
    double xd[BPT][D_];
    #pragma unroll
    for (int j = 0; j < BPT; ++j) {
        const int b = btile * BTILE + j * TPB + tid;
        const float4* xp = (const float4*)(x + (size_t)b * (C_ * D_) + c * D_);
        const float4 a = xp[0];
        const float4 h = xp[1];
        xd[j][0] = (double)a.x; xd[j][1] = (double)a.y;
        xd[j][2] = (double)a.z; xd[j][3] = (double)a.w;
        xd[j][4] = (double)h.x; xd[j][5] = (double)h.y;
        xd[j][6] = (double)h.z; xd[j][7] = (double)h.w;
    }

    double best[BPT];
    int    bidx[BPT];
    #pragma unroll
    for (int j = 0; j < BPT; ++j) { best[j] = 1.0e300; bidx[j] = 0; }

    // score = c2[k] - 2*dot, all fp64 -> true argmin (matches numpy exactly).
    // Strict < keeps the FIRST minimal index.
    for (int k = 0; k < K_; ++k) {
        double cd[D_];
        #pragma unroll
        for (int d = 0; d < D_; ++d) cd[d] = s_cbd[k * D_ + d];
        const double c2k = s_c2d[k];
        #pragma unroll
        for (int j = 0; j < BPT; ++j) {
            double dot = xd[j][0] * cd[0];
            #pragma unroll
            for (int d = 1; d < D_; ++d) dot = fma(xd[j][d], cd[d], dot);
            const double score = fma(-2.0, dot, c2k);
            const bool lt = score < best[j];
            best[j] = lt ? score : best[j];
            bidx[j] = lt ? k : bidx[j];
        }
    }

    #pragma unroll
    for (int j = 0; j < BPT; ++j) {
        const int b = btile * BTILE + j * TPB + tid;
        idx_out[(size_t)b * C_ + c] = bidx[j];
    }
}

// ---------------- K2: coalesced streaming writer ----------------
// Each wave writes one 1KB one-hot row per store instr (lane l = float4 #l).
// Embed rows (32B/pair, pairs linear) written coalesced; codewords gathered
// from the L2-resident 1MB codebook.
constexpr int GRID2 = 2048;
constexpr int RPB   = (B_ * C_) / GRID2;  // 256 rows (pairs) per block

__global__ __launch_bounds__(TPB, 4) void vq_write(
    const int*   __restrict__ idx,
    const float* __restrict__ cb,
    float* __restrict__ out_embed,
    float* __restrict__ out_onehot)
{
    const int tid  = threadIdx.x;
    const int lane = tid & 63;
    const int wave = tid >> 6;
    const int blk  = blockIdx.x;

    // ---- one-hot: 64 consecutive rows per wave ----
    const int rowbase = blk * RPB + wave * 64;
    const int myk = idx[rowbase + lane];  // one coalesced load per wave
    const int e0 = lane * 4;
    #pragma unroll 4
    for (int i = 0; i < 64; ++i) {
        const int k = __builtin_amdgcn_readlane(myk, i);  // scalar broadcast
        float4 v;
        v.x = (k == e0    ) ? 1.f : 0.f;
        v.y = (k == e0 + 1) ? 1.f : 0.f;
        v.z = (k == e0 + 2) ? 1.f : 0.f;
        v.w = (k == e0 + 3) ? 1.f : 0.f;
        ((float4*)(out_onehot + (size_t)(rowbase + i) * K_))[lane] = v;
    }

    // ---- embed: 256 pairs per block = 512 float4, 2 per thread ----
    const size_t pbase = (size_t)blk * RPB;
    #pragma unroll
    for (int i = 0; i < 2; ++i) {
        const int    f    = i * TPB + tid;   // 0..511
        const int    pl   = f >> 1;
        const int    half = f & 1;
        const size_t pair = pbase + pl;
        const int    c    = (int)(pair & (C_ - 1));
        const int    k    = idx[pair];
        const float4 val  = ((const float4*)(cb + ((size_t)c * K_ + k) * D_))[half];
        ((float4*)(out_embed + pbase * D_))[f] = val;
    }
}

extern "C" void kernel_launch(void* const* d_in, const int* in_sizes, int n_in,
                              void* d_out, int out_size, void* d_ws, size_t ws_size,
                              hipStream_t stream) {
    const float* x  = (const float*)d_in[0];
    const float* cb = (const float*)d_in[1];
    float* out        = (float*)d_out;
    float* out_embed  = out;                          // 4096*1024
    float* out_onehot = out + (size_t)B_ * C_ * D_;   // 4096*128*256
    int*   idx_ws     = (int*)d_ws;                   // 4096*128 ints = 2 MB

    dim3 grid1(C_, B_ / BTILE);  // (128, 4)
    vq_argmin<<<grid1, TPB, 0, stream>>>(x, cb, idx_ws);

    vq_write<<<GRID2, TPB, 0, stream>>>(idx_ws, cb, out_embed, out_onehot);
}

// Round 4
// 602.852 us; speedup vs baseline: 1.1792x; 1.0248x over previous
//
#include <hip/hip_runtime.h>

// VQ-VAE codebook quantization — 3-kernel: fp32 screen + fp64 repair + writer.
// x: (4096, 1024) f32; codebook: (128, 256, 8) f32.
// out = [cw_embed (4096*1024 f32) | one_hot (4096*128*256 f32)].
//
// R3 post-mortem: fp64 argmin was ~170+ us (half-rate fp64, 64b selects, only
// 2 waves/SIMD). Fix: fp32 top-2 screen (provably safe: fp32 score error
// <= ~6.4e-5 worst case; ambiguity threshold 1e-3 gives 8x margin) flags ~5%
// of pairs via idx bit31; a cheap wave-per-pair fp64 pass repairs flagged
// pairs exactly (same formula that scored absmax 0.0 in R2/R3). Writer
// streams 554MB coalesced (1KB/row per wave-store).

constexpr int B_  = 4096;
constexpr int C_  = 128;
constexpr int K_  = 256;
constexpr int D_  = 8;
constexpr int TPB = 256;
constexpr int NP  = B_ * C_;   // 524288 pairs

typedef float  vf4 __attribute__((ext_vector_type(4)));

// ---------------- Pass 1: fp32 top-2 screen ----------------
constexpr int   BPT1   = 2;            // b's per thread
constexpr int   BTILE1 = TPB * BPT1;   // 512 b per block
constexpr float TAU2   = 1.0e-3f;      // ambiguity gap threshold (2*tau)

__global__ __launch_bounds__(TPB, 4) void vq_screen(
    const float* __restrict__ x,
    const float* __restrict__ cb,
    int* __restrict__ idx_out)
{
    __shared__ float s_cbf[K_ * D_];  // 8 KB fp32 codebook slice
    __shared__ float s_c2f[K_];       // 1 KB fp32 ||c_k||^2

    const int c     = blockIdx.x;  // 0..127
    const int btile = blockIdx.y;  // 0..7
    const int tid   = threadIdx.x;

    {
        const float4* gcb = (const float4*)(cb + (size_t)c * (K_ * D_));
        ((float4*)s_cbf)[tid]       = gcb[tid];
        ((float4*)s_cbf)[tid + TPB] = gcb[tid + TPB];
    }
    __syncthreads();
    {
        const float* v = s_cbf + tid * D_;
        float s = 0.f;
        #pragma unroll
        for (int d = 0; d < D_; ++d) s = fmaf(v[d], v[d], s);
        s_c2f[tid] = s;
    }
    __syncthreads();

    float xf[BPT1][D_];
    #pragma unroll
    for (int j = 0; j < BPT1; ++j) {
        const int b = btile * BTILE1 + j * TPB + tid;
        const float4* xp = (const float4*)(x + (size_t)b * (C_ * D_) + c * D_);
        const float4 a = xp[0];
        const float4 h = xp[1];
        xf[j][0] = a.x; xf[j][1] = a.y; xf[j][2] = a.z; xf[j][3] = a.w;
        xf[j][4] = h.x; xf[j][5] = h.y; xf[j][6] = h.z; xf[j][7] = h.w;
    }

    float s1[BPT1], s2[BPT1];
    int   k1[BPT1];
    #pragma unroll
    for (int j = 0; j < BPT1; ++j) { s1[j] = 3.4e38f; s2[j] = 3.4e38f; k1[j] = 0; }

    const float4* scb4 = (const float4*)s_cbf;
    #pragma unroll 2
    for (int k = 0; k < K_; ++k) {
        const float4 clo = scb4[k * 2];
        const float4 chi = scb4[k * 2 + 1];
        const float  c2k = s_c2f[k];
        #pragma unroll
        for (int j = 0; j < BPT1; ++j) {
            float dot = xf[j][0] * clo.x;
            dot = fmaf(xf[j][1], clo.y, dot);
            dot = fmaf(xf[j][2], clo.z, dot);
            dot = fmaf(xf[j][3], clo.w, dot);
            dot = fmaf(xf[j][4], chi.x, dot);
            dot = fmaf(xf[j][5], chi.y, dot);
            dot = fmaf(xf[j][6], chi.z, dot);
            dot = fmaf(xf[j][7], chi.w, dot);
            const float score = fmaf(-2.f, dot, c2k);
            // top-2 (s2 uses OLD s1; strict < keeps first-index winner)
            s2[j] = fminf(s2[j], fmaxf(score, s1[j]));
            const bool lt = score < s1[j];
            k1[j] = lt ? k : k1[j];
            s1[j] = lt ? score : s1[j];
        }
    }

    #pragma unroll
    for (int j = 0; j < BPT1; ++j) {
        const int b = btile * BTILE1 + j * TPB + tid;
        const bool amb = (s2[j] - s1[j]) <= TAU2;  // fp64 could reorder -> flag
        idx_out[(size_t)b * C_ + c] = k1[j] | (amb ? (1 << 31) : 0);
    }
}

// ---------------- Pass 2: fp64 repair of flagged pairs ----------------
// One full wave per flagged pair: 4 codes/lane in fp64 (exact formula from
// the R2/R3 kernel that matched np with absmax 0.0), first-index tie-break.
constexpr int FIXBLKS = 256;

__global__ __launch_bounds__(TPB, 4) void vq_fix(
    const float* __restrict__ x,
    const float* __restrict__ cb,
    int* __restrict__ idx)
{
    const int lane   = threadIdx.x & 63;
    const int gwave  = (blockIdx.x * TPB + threadIdx.x) >> 6;
    const int nwaves = (FIXBLKS * TPB) >> 6;  // 1024

    for (int base = gwave * 64; base < NP; base += nwaves * 64) {
        const int v = idx[base + lane];
        unsigned long long mask = __ballot(v < 0);
        while (mask) {
            const int src = (int)__ffsll((long long)mask) - 1;
            mask &= mask - 1;
            const int pair = base + src;
            const int b = pair >> 7;        // /C_
            const int c = pair & (C_ - 1);

            const float* xp = x  + (size_t)b * (C_ * D_) + c * D_;
            const float* cp = cb + (size_t)c * (K_ * D_);

            double xd[D_];
            #pragma unroll
            for (int d = 0; d < D_; ++d) xd[d] = (double)xp[d];

            double best = 1.0e300;
            int    bk   = 0;
            #pragma unroll
            for (int t = 0; t < 4; ++t) {
                const int k = lane * 4 + t;   // ascending k within lane
                const float* cv = cp + k * D_;
                double cd[D_];
                #pragma unroll
                for (int d = 0; d < D_; ++d) cd[d] = (double)cv[d];
                double c2k = 0.0;
                #pragma unroll
                for (int d = 0; d < D_; ++d) c2k = fma(cd[d], cd[d], c2k);
                double dot = xd[0] * cd[0];
                #pragma unroll
                for (int d = 1; d < D_; ++d) dot = fma(xd[d], cd[d], dot);
                const double score = fma(-2.0, dot, c2k);
                if (score < best) { best = score; bk = k; }  // first-min
            }
            // reduce: strictly smaller wins; tie -> lower lane (= lower k)
            #pragma unroll
            for (int off = 32; off >= 1; off >>= 1) {
                const double ob  = __shfl_down(best, off);
                const int    obk = __shfl_down(bk,   off);
                if (ob < best) { best = ob; bk = obk; }
            }
            if (lane == 0) idx[pair] = bk;   // clears bit31 too
        }
    }
}

// ---------------- Pass 3: coalesced streaming writer ----------------
constexpr int GRID3 = 2048;
constexpr int RPB   = NP / GRID3;  // 256 rows per block

__global__ __launch_bounds__(TPB, 4) void vq_write(
    const int*   __restrict__ idx,
    const float* __restrict__ cb,
    float* __restrict__ out_embed,
    float* __restrict__ out_onehot)
{
    const int tid  = threadIdx.x;
    const int lane = tid & 63;
    const int wave = tid >> 6;
    const int blk  = blockIdx.x;

    // one-hot: 64 consecutive rows per wave, 1KB contiguous per store instr
    const int rowbase = blk * RPB + wave * 64;
    const int myk = idx[rowbase + lane];
    const int e0 = lane * 4;
    #pragma unroll 4
    for (int i = 0; i < 64; ++i) {
        const int k = __builtin_amdgcn_readlane(myk, i);
        vf4 v;
        v.x = (k == e0    ) ? 1.f : 0.f;
        v.y = (k == e0 + 1) ? 1.f : 0.f;
        v.z = (k == e0 + 2) ? 1.f : 0.f;
        v.w = (k == e0 + 3) ? 1.f : 0.f;
        vf4* dst = (vf4*)(out_onehot + (size_t)(rowbase + i) * K_) + lane;
        __builtin_nontemporal_store(v, dst);
    }

    // embed: 256 pairs per block = 512 float4, 2 per thread, coalesced
    const size_t pbase = (size_t)blk * RPB;
    #pragma unroll
    for (int i = 0; i < 2; ++i) {
        const int    f    = i * TPB + tid;   // 0..511
        const int    pl   = f >> 1;
        const int    half = f & 1;
        const size_t pair = pbase + pl;
        const int    c    = (int)(pair & (C_ - 1));
        const int    k    = idx[pair];
        const vf4 val = ((const vf4*)(cb + ((size_t)c * K_ + k) * D_))[half];
        __builtin_nontemporal_store(val, (vf4*)(out_embed + pbase * D_) + f);
    }
}

extern "C" void kernel_launch(void* const* d_in, const int* in_sizes, int n_in,
                              void* d_out, int out_size, void* d_ws, size_t ws_size,
                              hipStream_t stream) {
    const float* x  = (const float*)d_in[0];
    const float* cb = (const float*)d_in[1];
    float* out        = (float*)d_out;
    float* out_embed  = out;                          // 4096*1024
    float* out_onehot = out + (size_t)B_ * C_ * D_;   // 4096*128*256
    int*   idx_ws     = (int*)d_ws;                   // 524288 ints = 2 MB

    dim3 grid1(C_, B_ / BTILE1);  // (128, 8) = 1024 blocks
    vq_screen<<<grid1, TPB, 0, stream>>>(x, cb, idx_ws);

    vq_fix<<<FIXBLKS, TPB, 0, stream>>>(x, cb, idx_ws);

    vq_write<<<GRID3, TPB, 0, stream>>>(idx_ws, cb, out_embed, out_onehot);
}